// Round 9
// baseline (1165.279 us; speedup 1.0000x reference)
//
#include <hip/hip_runtime.h>

#define R_ 8
#define N_ 40000
#define F_ 128
#define E_ 160000
#define NE (R_ * E_)   // 1,280,000 edges
#define NBUK 625       // src>>6 buckets (64 rows each), 625*64 = 40000 exactly
#define FBLK 320       // edge chunks
#define FCHUNK 4000    // FBLK * FCHUNK == NE exactly

typedef unsigned short ushort;
typedef unsigned int uint;
typedef unsigned char uchar;
typedef __attribute__((ext_vector_type(8))) short bf16x8;
typedef __attribute__((ext_vector_type(4))) float f32x4;

// fp32 -> bf16 round-to-nearest-even (returns bit pattern)
__device__ __forceinline__ ushort f2bf(float x) {
    uint u = __float_as_uint(x);
    return (ushort)((u + 0x7fffu + ((u >> 16) & 1u)) >> 16);
}

// --- K0: Wt = bf16(W^T), 128x128, one block ---
__global__ __launch_bounds__(256) void wtconv_kernel(const float* __restrict__ W,
                                                     ushort* __restrict__ Wt) {
    __shared__ ushort l[128 * 128];     // 32 KB
    int t = threadIdx.x;
#pragma unroll
    for (int p = 0; p < 16; ++p) {      // 4096 float4 reads, coalesced
        int idx = p * 256 + t;
        int k = idx >> 5;               // source row of W
        int c4 = (idx & 31) * 4;        // source cols
        float4 v = ((const float4*)W)[idx];
        l[(c4 + 0) * 128 + k] = f2bf(v.x);
        l[(c4 + 1) * 128 + k] = f2bf(v.y);
        l[(c4 + 2) * 128 + k] = f2bf(v.z);
        l[(c4 + 3) * 128 + k] = f2bf(v.w);
    }
    __syncthreads();
#pragma unroll
    for (int p = 0; p < 8; ++p) {       // 2048 16B writes, coalesced
        int idx = p * 256 + t;
        ((float4*)Wt)[idx] = ((const float4*)l)[idx];
    }
}

// --- K1: fused independent prep ---
// blocks [0,625):    proj = ent @ W via bf16 MFMA (64 rows/block), B-frags from global Wt
// block  625:        rel_mat passthrough to out tail
// blocks [626,630):  alpha MLP (2 relations/block)
// blocks [630,950):  fillA — per-chunk bucket histogram (625 buckets)
__global__ __launch_bounds__(256) void fused_prep(
        const float* __restrict__ ent, const ushort* __restrict__ Wt,
        ushort* __restrict__ proj,
        const int* __restrict__ esrc,
        const float* __restrict__ rel, float* __restrict__ out_tail,
        const float* __restrict__ w1, const float* __restrict__ b1,
        const float* __restrict__ w2, float* __restrict__ alpha,
        int* __restrict__ hist) {
    __shared__ float smem[1024];        // 4 KB: alpha red / fillA hist (int alias)
    const int t = threadIdx.x;
    const int b = blockIdx.x;
    if (b < 625) {
        const int wv_ = t >> 6;          // wave 0..3
        const int lane = t & 63;
        const int m = lane & 15;
        const int q = (lane >> 4) & 3;
        const int row0 = b * 64 + wv_ * 16;
        bf16x8 afrag[4];
        const float* arow = ent + (size_t)(row0 + m) * F_;
#pragma unroll
        for (int kc = 0; kc < 4; ++kc) {
            float4 a0 = *(const float4*)&arow[kc * 32 + q * 8];
            float4 a1 = *(const float4*)&arow[kc * 32 + q * 8 + 4];
            bf16x8 a;
            a[0] = (short)f2bf(a0.x); a[1] = (short)f2bf(a0.y);
            a[2] = (short)f2bf(a0.z); a[3] = (short)f2bf(a0.w);
            a[4] = (short)f2bf(a1.x); a[5] = (short)f2bf(a1.y);
            a[6] = (short)f2bf(a1.z); a[7] = (short)f2bf(a1.w);
            afrag[kc] = a;
        }
        f32x4 acc[8];
#pragma unroll
        for (int ct = 0; ct < 8; ++ct) acc[ct] = (f32x4){0.f, 0.f, 0.f, 0.f};
#pragma unroll
        for (int ct = 0; ct < 8; ++ct) {
            int n = ct * 16 + m;         // Wt row = W column
#pragma unroll
            for (int kc = 0; kc < 4; ++kc) {
                bf16x8 bfrag = *(const bf16x8*)&Wt[n * F_ + kc * 32 + q * 8];
                acc[ct] = __builtin_amdgcn_mfma_f32_16x16x32_bf16(afrag[kc], bfrag, acc[ct], 0, 0, 0);
            }
        }
#pragma unroll
        for (int ct = 0; ct < 8; ++ct) {
#pragma unroll
            for (int reg = 0; reg < 4; ++reg) {
                int row = row0 + q * 4 + reg;
                proj[(size_t)row * F_ + ct * 16 + m] = f2bf(acc[ct][reg]);
            }
        }
    } else if (b == 625) {
        ((float4*)out_tail)[t] = ((const float4*)rel)[t];   // 1024 floats
    } else if (b < 630) {
        int r = (b - 626) * 2 + (t >> 7);
        int o = t & 127;
        float s = 0.f;
#pragma unroll 8
        for (int f = 0; f < F_; ++f) s += rel[r * F_ + f] * w1[f * F_ + o];
        float h = tanhf(s + b1[o]);
        smem[t] = h * w2[o];
        __syncthreads();
        for (int off = 64; off > 0; off >>= 1) {
            if ((t & 127) < off) smem[t] += smem[t + off];
            __syncthreads();
        }
        if ((t & 127) == 0) alpha[r] = 1.f / (1.f + expf(-smem[t]));
    } else {
        // fillA: bucket histogram for chunk hb; hist transposed [bucket][chunk]
        int hb = b - 630;
        int* h = (int*)smem;
        for (int i = t; i < NBUK; i += 256) h[i] = 0;
        __syncthreads();
        int base = hb * FCHUNK;
        for (int i = t; i < FCHUNK; i += 256)
            atomicAdd(&h[esrc[base + i] >> 6], 1);
        __syncthreads();
        for (int i = t; i < NBUK; i += 256) hist[i * FBLK + hb] = h[i];
    }
}

// --- K2: per bucket, exclusive-scan the FBLK chunk counts (bucket-relative) + total ---
__global__ __launch_bounds__(FBLK) void fillscan_kernel(const int* __restrict__ hist,
                                                        int* __restrict__ blockbase,
                                                        int* __restrict__ total) {
    __shared__ int sc[FBLK];
    int b = blockIdx.x, t = threadIdx.x;
    int own = hist[b * FBLK + t];       // coalesced
    sc[t] = own;
    __syncthreads();
    for (int off = 1; off < FBLK; off <<= 1) {
        int v = (t >= off) ? sc[t - off] : 0;
        __syncthreads();
        sc[t] += v;
        __syncthreads();
    }
    blockbase[b * FBLK + t] = sc[t] - own;     // exclusive, bucket-relative
    if (t == FBLK - 1) total[b] = sc[t];
}

// --- K3: scan 625 bucket totals -> bucketbase[0..625] ---
__global__ __launch_bounds__(1024) void bucketscan_kernel(const int* __restrict__ total,
                                                          int* __restrict__ bucketbase) {
    __shared__ int sc[1024];
    int t = threadIdx.x;
    int v = (t < NBUK) ? total[t] : 0;
    sc[t] = v;
    __syncthreads();
    for (int off = 1; off < 1024; off <<= 1) {
        int u = (t >= off) ? sc[t - off] : 0;
        __syncthreads();
        sc[t] += u;
        __syncthreads();
    }
    if (t < NBUK) bucketbase[t] = sc[t] - v;
    if (t == NBUK - 1) bucketbase[NBUK] = sc[t];   // == NE
}

// --- K4: fillB — bucket-sort edges: payload (dst|bf16w) + src-in-bucket byte ---
__global__ __launch_bounds__(256) void fillB_kernel(const int* __restrict__ esrc,
                                                    const int* __restrict__ edst,
                                                    const float* __restrict__ eval_,
                                                    const float* __restrict__ alpha,
                                                    const int* __restrict__ blockbase,
                                                    const int* __restrict__ bucketbase,
                                                    uint* __restrict__ payload,
                                                    uchar* __restrict__ srcb) {
    __shared__ int lcnt[NBUK];
    __shared__ int lbase[NBUK];
    int t = threadIdx.x, blk = blockIdx.x;
    for (int i = t; i < NBUK; i += 256) {
        lcnt[i] = 0;
        lbase[i] = bucketbase[i] + blockbase[i * FBLK + blk];
    }
    __syncthreads();
    int base = blk * FCHUNK;
    for (int i = t; i < FCHUNK; i += 256) {
        int e = base + i;
        int s = esrc[e];
        int d = edst[e];
        float w = alpha[e / E_] * eval_[e];
        int bk = s >> 6;
        int idx = lbase[bk] + atomicAdd(&lcnt[bk], 1);
        payload[idx] = (uint)d | ((uint)f2bf(w) << 16);
        srcb[idx] = (uchar)(s & 63);
    }
}

// --- K5: spmm_tile — block = 64-row bucket, LDS fp32 atomic accumulation ---
__global__ __launch_bounds__(512) void spmm_tile(const uint* __restrict__ payload,
                                                 const uchar* __restrict__ srcb,
                                                 const int* __restrict__ bucketbase,
                                                 const ushort* __restrict__ proj,
                                                 float* __restrict__ out) {
    __shared__ float tile[64 * F_];     // 32 KB
    int t = threadIdx.x, b = blockIdx.x;
#pragma unroll
    for (int i = 0; i < 16; ++i) tile[i * 512 + t] = 0.f;
    __syncthreads();
    int beg = bucketbase[b], end = bucketbase[b + 1];
    int cnt = end - beg;
    int wv = t >> 6, lane = t & 63;
    int span = (cnt + 7) >> 3;
    int j = beg + wv * span;
    int j1 = min(j + span, end);
    for (; j + 4 <= j1; j += 4) {
        uint e0 = payload[j], e1 = payload[j + 1], e2 = payload[j + 2], e3 = payload[j + 3];
        int s0 = srcb[j], s1 = srcb[j + 1], s2 = srcb[j + 2], s3 = srcb[j + 3];
        // cols lane and lane+64: 2-lanes/bank LDS pattern (free), 128B-coalesced gathers
        ushort p0a = proj[((e0 & 0xffffu) << 7) + lane], p0b = proj[((e0 & 0xffffu) << 7) + 64 + lane];
        ushort p1a = proj[((e1 & 0xffffu) << 7) + lane], p1b = proj[((e1 & 0xffffu) << 7) + 64 + lane];
        ushort p2a = proj[((e2 & 0xffffu) << 7) + lane], p2b = proj[((e2 & 0xffffu) << 7) + 64 + lane];
        ushort p3a = proj[((e3 & 0xffffu) << 7) + lane], p3b = proj[((e3 & 0xffffu) << 7) + 64 + lane];
        float w0 = __uint_as_float(e0 & 0xffff0000u);
        float w1 = __uint_as_float(e1 & 0xffff0000u);
        float w2 = __uint_as_float(e2 & 0xffff0000u);
        float w3 = __uint_as_float(e3 & 0xffff0000u);
        atomicAdd(&tile[(s0 << 7) + lane],      w0 * __uint_as_float((uint)p0a << 16));
        atomicAdd(&tile[(s0 << 7) + 64 + lane], w0 * __uint_as_float((uint)p0b << 16));
        atomicAdd(&tile[(s1 << 7) + lane],      w1 * __uint_as_float((uint)p1a << 16));
        atomicAdd(&tile[(s1 << 7) + 64 + lane], w1 * __uint_as_float((uint)p1b << 16));
        atomicAdd(&tile[(s2 << 7) + lane],      w2 * __uint_as_float((uint)p2a << 16));
        atomicAdd(&tile[(s2 << 7) + 64 + lane], w2 * __uint_as_float((uint)p2b << 16));
        atomicAdd(&tile[(s3 << 7) + lane],      w3 * __uint_as_float((uint)p3a << 16));
        atomicAdd(&tile[(s3 << 7) + 64 + lane], w3 * __uint_as_float((uint)p3b << 16));
    }
    for (; j < j1; ++j) {
        uint e = payload[j];
        int s = srcb[j];
        ushort pa = proj[((e & 0xffffu) << 7) + lane], pb = proj[((e & 0xffffu) << 7) + 64 + lane];
        float w = __uint_as_float(e & 0xffff0000u);
        atomicAdd(&tile[(s << 7) + lane],      w * __uint_as_float((uint)pa << 16));
        atomicAdd(&tile[(s << 7) + 64 + lane], w * __uint_as_float((uint)pb << 16));
    }
    __syncthreads();
    const float4* tl = (const float4*)tile;
    float4* op = (float4*)(out + ((size_t)b << 13));   // b*64*128
#pragma unroll
    for (int i = 0; i < 4; ++i) op[i * 512 + t] = tl[i * 512 + t];
}

extern "C" void kernel_launch(void* const* d_in, const int* in_sizes, int n_in,
                              void* d_out, int out_size, void* d_ws, size_t ws_size,
                              hipStream_t stream) {
    const float* ent   = (const float*)d_in[0];
    const float* rel   = (const float*)d_in[1];
    const int*   esrc  = (const int*)d_in[2];
    const int*   edst  = (const int*)d_in[3];
    const float* eval_ = (const float*)d_in[4];
    const float* went  = (const float*)d_in[5];
    const float* w1    = (const float*)d_in[6];
    const float* b1    = (const float*)d_in[7];
    const float* w2    = (const float*)d_in[8];

    float* out      = (float*)d_out;
    float* out_tail = out + (size_t)N_ * F_;

    char* ws = (char*)d_ws;
    size_t off = 0;
    ushort* proj      = (ushort*)(ws + off); off += (size_t)N_ * F_ * 2;      // 10.24 MB
    ushort* Wt        = (ushort*)(ws + off); off += (size_t)F_ * F_ * 2;      // 32 KB
    float*  alpha     = (float*)(ws + off);  off += 256;
    uint*   payload   = (uint*)(ws + off);   off += (size_t)NE * 4;           // 5.12 MB
    uchar*  srcb      = (uchar*)(ws + off);  off += (size_t)NE + 256;         // 1.28 MB
    int*    hist      = (int*)(ws + off);    off += (size_t)NBUK * FBLK * 4;  // 800 KB
    int*    blockbase = (int*)(ws + off);    off += (size_t)NBUK * FBLK * 4;  // 800 KB
    int*    total     = (int*)(ws + off);    off += (size_t)(NBUK + 7) * 4;
    int*    bucketbase= (int*)(ws + off);    off += (size_t)(NBUK + 7) * 4;

    wtconv_kernel<<<1, 256, 0, stream>>>(went, Wt);
    fused_prep<<<950, 256, 0, stream>>>(ent, Wt, proj, esrc,
                                        rel, out_tail, w1, b1, w2, alpha, hist);
    fillscan_kernel<<<NBUK, FBLK, 0, stream>>>(hist, blockbase, total);
    bucketscan_kernel<<<1, 1024, 0, stream>>>(total, bucketbase);
    fillB_kernel<<<FBLK, 256, 0, stream>>>(esrc, edst, eval_, alpha,
                                           blockbase, bucketbase, payload, srcb);
    spmm_tile<<<NBUK, 512, 0, stream>>>(payload, srcb, bucketbase, proj, out);
}

// Round 10
// 192.534 us; speedup vs baseline: 6.0523x; 6.0523x over previous
//
#include <hip/hip_runtime.h>

#define R_ 8
#define N_ 40000
#define F_ 128
#define E_ 160000
#define NE (R_ * E_)   // 1,280,000 edges
#define NBUK 313       // src>>7 buckets (128 rows each), 313*128 = 40064 >= N_
#define FBLK 320       // edge chunks
#define FCHUNK 4000    // FBLK * FCHUNK == NE exactly

typedef unsigned short ushort;
typedef unsigned int uint;
typedef unsigned char uchar;
typedef __attribute__((ext_vector_type(8))) short bf16x8;
typedef __attribute__((ext_vector_type(4))) float f32x4;

// fp32 -> bf16 round-to-nearest-even (returns bit pattern)
__device__ __forceinline__ ushort f2bf(float x) {
    uint u = __float_as_uint(x);
    return (ushort)((u + 0x7fffu + ((u >> 16) & 1u)) >> 16);
}

// --- K0: Wt = bf16(W^T), 128x128, one block ---
__global__ __launch_bounds__(256) void wtconv_kernel(const float* __restrict__ W,
                                                     ushort* __restrict__ Wt) {
    __shared__ ushort l[128 * 128];     // 32 KB
    int t = threadIdx.x;
#pragma unroll
    for (int p = 0; p < 16; ++p) {      // 4096 float4 reads, coalesced
        int idx = p * 256 + t;
        int k = idx >> 5;               // source row of W
        int c4 = (idx & 31) * 4;        // source cols
        float4 v = ((const float4*)W)[idx];
        l[(c4 + 0) * 128 + k] = f2bf(v.x);
        l[(c4 + 1) * 128 + k] = f2bf(v.y);
        l[(c4 + 2) * 128 + k] = f2bf(v.z);
        l[(c4 + 3) * 128 + k] = f2bf(v.w);
    }
    __syncthreads();
#pragma unroll
    for (int p = 0; p < 8; ++p) {       // 2048 16B writes, coalesced
        int idx = p * 256 + t;
        ((float4*)Wt)[idx] = ((const float4*)l)[idx];
    }
}

// --- K1: fused independent prep ---
// blocks [0,625):    proj = ent @ W via bf16 MFMA (64 rows/block), B-frags from global Wt
// block  625:        rel_mat passthrough to out tail
// blocks [626,630):  alpha MLP (2 relations/block)
// blocks [630,950):  fillA — per-chunk bucket histogram (313 buckets)
__global__ __launch_bounds__(256) void fused_prep(
        const float* __restrict__ ent, const ushort* __restrict__ Wt,
        ushort* __restrict__ proj,
        const int* __restrict__ esrc,
        const float* __restrict__ rel, float* __restrict__ out_tail,
        const float* __restrict__ w1, const float* __restrict__ b1,
        const float* __restrict__ w2, float* __restrict__ alpha,
        int* __restrict__ hist) {
    __shared__ float smem[1024];        // 4 KB: alpha red / fillA hist (int alias)
    const int t = threadIdx.x;
    const int b = blockIdx.x;
    if (b < 625) {
        const int wv_ = t >> 6;          // wave 0..3
        const int lane = t & 63;
        const int m = lane & 15;
        const int q = (lane >> 4) & 3;
        const int row0 = b * 64 + wv_ * 16;
        bf16x8 afrag[4];
        const float* arow = ent + (size_t)(row0 + m) * F_;
#pragma unroll
        for (int kc = 0; kc < 4; ++kc) {
            float4 a0 = *(const float4*)&arow[kc * 32 + q * 8];
            float4 a1 = *(const float4*)&arow[kc * 32 + q * 8 + 4];
            bf16x8 a;
            a[0] = (short)f2bf(a0.x); a[1] = (short)f2bf(a0.y);
            a[2] = (short)f2bf(a0.z); a[3] = (short)f2bf(a0.w);
            a[4] = (short)f2bf(a1.x); a[5] = (short)f2bf(a1.y);
            a[6] = (short)f2bf(a1.z); a[7] = (short)f2bf(a1.w);
            afrag[kc] = a;
        }
        f32x4 acc[8];
#pragma unroll
        for (int ct = 0; ct < 8; ++ct) acc[ct] = (f32x4){0.f, 0.f, 0.f, 0.f};
#pragma unroll
        for (int ct = 0; ct < 8; ++ct) {
            int n = ct * 16 + m;         // Wt row = W column
#pragma unroll
            for (int kc = 0; kc < 4; ++kc) {
                bf16x8 bfrag = *(const bf16x8*)&Wt[n * F_ + kc * 32 + q * 8];
                acc[ct] = __builtin_amdgcn_mfma_f32_16x16x32_bf16(afrag[kc], bfrag, acc[ct], 0, 0, 0);
            }
        }
#pragma unroll
        for (int ct = 0; ct < 8; ++ct) {
#pragma unroll
            for (int reg = 0; reg < 4; ++reg) {
                int row = row0 + q * 4 + reg;
                proj[(size_t)row * F_ + ct * 16 + m] = f2bf(acc[ct][reg]);
            }
        }
    } else if (b == 625) {
        ((float4*)out_tail)[t] = ((const float4*)rel)[t];   // 1024 floats
    } else if (b < 630) {
        int r = (b - 626) * 2 + (t >> 7);
        int o = t & 127;
        float s = 0.f;
#pragma unroll 8
        for (int f = 0; f < F_; ++f) s += rel[r * F_ + f] * w1[f * F_ + o];
        float h = tanhf(s + b1[o]);
        smem[t] = h * w2[o];
        __syncthreads();
        for (int off = 64; off > 0; off >>= 1) {
            if ((t & 127) < off) smem[t] += smem[t + off];
            __syncthreads();
        }
        if ((t & 127) == 0) alpha[r] = 1.f / (1.f + expf(-smem[t]));
    } else {
        // fillA: bucket histogram for chunk hb; hist transposed [bucket][chunk]
        int hb = b - 630;
        int* h = (int*)smem;
        for (int i = t; i < NBUK; i += 256) h[i] = 0;
        __syncthreads();
        int base = hb * FCHUNK;
        for (int i = t; i < FCHUNK; i += 256)
            atomicAdd(&h[esrc[base + i] >> 7], 1);
        __syncthreads();
        for (int i = t; i < NBUK; i += 256) hist[i * FBLK + hb] = h[i];
    }
}

// --- K2: per bucket, exclusive-scan the FBLK chunk counts (bucket-relative) + total ---
__global__ __launch_bounds__(FBLK) void fillscan_kernel(const int* __restrict__ hist,
                                                        int* __restrict__ blockbase,
                                                        int* __restrict__ total) {
    __shared__ int sc[FBLK];
    int b = blockIdx.x, t = threadIdx.x;
    int own = hist[b * FBLK + t];       // coalesced
    sc[t] = own;
    __syncthreads();
    for (int off = 1; off < FBLK; off <<= 1) {
        int v = (t >= off) ? sc[t - off] : 0;
        __syncthreads();
        sc[t] += v;
        __syncthreads();
    }
    blockbase[b * FBLK + t] = sc[t] - own;     // exclusive, bucket-relative
    if (t == FBLK - 1) total[b] = sc[t];
}

// --- K3: scan 313 bucket totals -> bucketbase[0..313] ---
__global__ __launch_bounds__(512) void bucketscan_kernel(const int* __restrict__ total,
                                                         int* __restrict__ bucketbase) {
    __shared__ int sc[512];
    int t = threadIdx.x;
    int v = (t < NBUK) ? total[t] : 0;
    sc[t] = v;
    __syncthreads();
    for (int off = 1; off < 512; off <<= 1) {
        int u = (t >= off) ? sc[t - off] : 0;
        __syncthreads();
        sc[t] += u;
        __syncthreads();
    }
    if (t < NBUK) bucketbase[t] = sc[t] - v;
    if (t == NBUK - 1) bucketbase[NBUK] = sc[t];   // == NE
}

// --- K4: fillB — bucket-sort edges: payload (dst|bf16w) + row-in-bucket byte ---
__global__ __launch_bounds__(256) void fillB_kernel(const int* __restrict__ esrc,
                                                    const int* __restrict__ edst,
                                                    const float* __restrict__ eval_,
                                                    const float* __restrict__ alpha,
                                                    const int* __restrict__ blockbase,
                                                    const int* __restrict__ bucketbase,
                                                    uint* __restrict__ payload,
                                                    uchar* __restrict__ srcb) {
    __shared__ int lcnt[NBUK];
    __shared__ int lbase[NBUK];
    int t = threadIdx.x, blk = blockIdx.x;
    for (int i = t; i < NBUK; i += 256) {
        lcnt[i] = 0;
        lbase[i] = bucketbase[i] + blockbase[i * FBLK + blk];
    }
    __syncthreads();
    int base = blk * FCHUNK;
    for (int i = t; i < FCHUNK; i += 256) {
        int e = base + i;
        int s = esrc[e];
        int d = edst[e];
        float w = alpha[e / E_] * eval_[e];
        int bk = s >> 7;
        int idx = lbase[bk] + atomicAdd(&lcnt[bk], 1);   // LDS int atomic: native, fast
        payload[idx] = (uint)d | ((uint)f2bf(w) << 16);
        srcb[idx] = (uchar)(s & 127);
    }
}

// --- K5: fillC — local row counts (LDS int atomics), rowptr emit, scatter to CSR ---
__global__ __launch_bounds__(256) void fillC_kernel(const uint* __restrict__ payload,
                                                    const uchar* __restrict__ srcb,
                                                    const int* __restrict__ bucketbase,
                                                    int* __restrict__ rowptr,
                                                    uint* __restrict__ sorted) {
    __shared__ int cnt128[128];
    __shared__ int cur[128];
    int b = blockIdx.x, t = threadIdx.x;
    if (t < 128) cnt128[t] = 0;
    __syncthreads();
    int beg = bucketbase[b], end = bucketbase[b + 1];
    for (int k = beg + t; k < end; k += 256)
        atomicAdd(&cnt128[srcb[k]], 1);                  // LDS int atomic: native
    __syncthreads();
    if (t < 128) cur[t] = cnt128[t];
    __syncthreads();
    for (int off = 1; off < 128; off <<= 1) {
        int v = 0;
        if (t < 128 && t >= off) v = cur[t - off];
        __syncthreads();
        if (t < 128) cur[t] += v;
        __syncthreads();
    }
    int excl = 0;
    if (t < 128) {
        excl = beg + cur[t] - cnt128[t];       // exclusive row start
        rowptr[(b << 7) + t] = excl;           // coalesced; pad rows get excl == end
    }
    __syncthreads();
    if (t < 128) cur[t] = excl;
    __syncthreads();
    for (int k = beg + t; k < end; k += 256) {
        uint pl = payload[k];
        int pos = atomicAdd(&cur[srcb[k]], 1);
        sorted[pos] = pl;       // confined to this bucket's ~16KB window
    }
}

// --- K6: CSR SpMM, wave/row, unroll-8 gathers, bf16 proj, fp32 accum ---
__global__ __launch_bounds__(256) void spmm_kernel(const int* __restrict__ rowptr,
                                                   const uint* __restrict__ sorted,
                                                   const ushort* __restrict__ proj,
                                                   float* __restrict__ out) {
    int wave = (blockIdx.x * 256 + threadIdx.x) >> 6;
    int lane = threadIdx.x & 63;
    int beg = __builtin_amdgcn_readfirstlane(rowptr[wave]);
    int end = __builtin_amdgcn_readfirstlane(rowptr[wave + 1]);
    float accx = 0.f, accy = 0.f;
    int j = beg;
    for (; j + 8 <= end; j += 8) {
        uint e[8], u[8];
#pragma unroll
        for (int i = 0; i < 8; ++i) e[i] = sorted[j + i];
#pragma unroll
        for (int i = 0; i < 8; ++i)
            u[i] = *(const uint*)&proj[((e[i] & 0xffffu) << 7) + 2 * lane];
#pragma unroll
        for (int i = 0; i < 8; ++i) {
            float w = __uint_as_float(e[i] & 0xffff0000u);
            accx += w * __uint_as_float(u[i] << 16);
            accy += w * __uint_as_float(u[i] & 0xffff0000u);
        }
    }
    for (; j < end; ++j) {
        uint e = sorted[j];
        uint u = *(const uint*)&proj[((e & 0xffffu) << 7) + 2 * lane];
        float w = __uint_as_float(e & 0xffff0000u);
        accx += w * __uint_as_float(u << 16);
        accy += w * __uint_as_float(u & 0xffff0000u);
    }
    *(float2*)&out[((size_t)wave << 7) + 2 * lane] = make_float2(accx, accy);
}

extern "C" void kernel_launch(void* const* d_in, const int* in_sizes, int n_in,
                              void* d_out, int out_size, void* d_ws, size_t ws_size,
                              hipStream_t stream) {
    const float* ent   = (const float*)d_in[0];
    const float* rel   = (const float*)d_in[1];
    const int*   esrc  = (const int*)d_in[2];
    const int*   edst  = (const int*)d_in[3];
    const float* eval_ = (const float*)d_in[4];
    const float* went  = (const float*)d_in[5];
    const float* w1    = (const float*)d_in[6];
    const float* b1    = (const float*)d_in[7];
    const float* w2    = (const float*)d_in[8];

    float* out      = (float*)d_out;
    float* out_tail = out + (size_t)N_ * F_;

    char* ws = (char*)d_ws;
    size_t off = 0;
    ushort* proj      = (ushort*)(ws + off); off += (size_t)N_ * F_ * 2;      // 10.24 MB
    ushort* Wt        = (ushort*)(ws + off); off += (size_t)F_ * F_ * 2;      // 32 KB
    float*  alpha     = (float*)(ws + off);  off += 256;
    uint*   payload   = (uint*)(ws + off);   off += (size_t)NE * 4;           // 5.12 MB
    uchar*  srcb      = (uchar*)(ws + off);  off += (size_t)NE + 256;         // 1.28 MB
    uint*   sorted    = (uint*)(ws + off);   off += (size_t)NE * 4;           // 5.12 MB
    int*    rowptr    = (int*)(ws + off);    off += (size_t)(N_ + 64) * 4;    // 160 KB
    int*    hist      = (int*)(ws + off);    off += (size_t)NBUK * FBLK * 4;  // 400 KB
    int*    blockbase = (int*)(ws + off);    off += (size_t)NBUK * FBLK * 4;  // 400 KB
    int*    total     = (int*)(ws + off);    off += (size_t)(NBUK + 7) * 4;
    int*    bucketbase= (int*)(ws + off);    off += (size_t)(NBUK + 7) * 4;

    wtconv_kernel<<<1, 256, 0, stream>>>(went, Wt);
    fused_prep<<<950, 256, 0, stream>>>(ent, Wt, proj, esrc,
                                        rel, out_tail, w1, b1, w2, alpha, hist);
    fillscan_kernel<<<NBUK, FBLK, 0, stream>>>(hist, blockbase, total);
    bucketscan_kernel<<<1, 512, 0, stream>>>(total, bucketbase);
    fillB_kernel<<<FBLK, 256, 0, stream>>>(esrc, edst, eval_, alpha,
                                           blockbase, bucketbase, payload, srcb);
    fillC_kernel<<<NBUK, 256, 0, stream>>>(payload, srcb, bucketbase, rowptr, sorted);
    spmm_kernel<<<(N_ * 64) / 256, 256, 0, stream>>>(rowptr, sorted, proj, out);
}